// Round 9
// baseline (435.917 us; speedup 1.0000x reference)
//
#include <hip/hip_runtime.h>
#include <math.h>

#define SEQ 2048
#define HID_DIM 2048
#define NH 16
#define NKV 4
#define HD 128
#define QS 3072   // fused qkv row stride (bf16): [q 2048 | k 512 | v 512]

typedef float  f4v  __attribute__((ext_vector_type(4)));
typedef __bf16 bf8v __attribute__((ext_vector_type(8)));
typedef __bf16 bf4v __attribute__((ext_vector_type(4)));
typedef __bf16 bf2v __attribute__((ext_vector_type(2)));

typedef __attribute__((address_space(1))) const void* gvp;
typedef __attribute__((address_space(3))) void*       svp;

__device__ __forceinline__ void gld16(const void* g, void* lds_wave_base) {
    __builtin_amdgcn_global_load_lds((gvp)g, (svp)lds_wave_base, 16, 0, 0);
}

// ---- fp32 -> bf16 converts ---------------------------------------------
__global__ __launch_bounds__(256)
void cvt_cat2(__bf16* __restrict__ dst, const float* __restrict__ s0,
              const float* __restrict__ s1, int rows, int kq)
{
    int i = blockIdx.x * 256 + threadIdx.x;
    if (i >= rows * kq * 2) return;
    int row = i / (2 * kq), c = i - row * 2 * kq;
    const float* s = (c < kq) ? s0 + ((size_t)row * kq + c) * 4
                              : s1 + ((size_t)row * kq + (c - kq)) * 4;
    float4 v = *reinterpret_cast<const float4*>(s);
    *reinterpret_cast<bf4v*>(dst + ((size_t)row * 2 * kq + c) * 4) =
        bf4v{ (__bf16)v.x, (__bf16)v.y, (__bf16)v.z, (__bf16)v.w };
}

__global__ __launch_bounds__(256)
void cvt(__bf16* __restrict__ dst, const float* __restrict__ src, int n4)
{
    int i = blockIdx.x * 256 + threadIdx.x;
    if (i >= n4) return;
    float4 v = *reinterpret_cast<const float4*>(src + (size_t)i * 4);
    *reinterpret_cast<bf4v*>(dst + (size_t)i * 4) =
        bf4v{ (__bf16)v.x, (__bf16)v.y, (__bf16)v.z, (__bf16)v.w };
}

// ---- split-K NT GEMM, 128x128 tile, bf16 partials ----------------------
__global__ __launch_bounds__(256)
void gemm_nt_sp(const __bf16* __restrict__ A, const __bf16* __restrict__ B,
                __bf16* __restrict__ P, int M, int N, int K, int KS)
{
    __shared__ __bf16 As[128 * 32];
    __shared__ __bf16 Bs[128 * 32];
    const int tid = threadIdx.x, lane = tid & 63, w = tid >> 6;
    const int wm = w >> 1, wn = w & 1;
    const int mm = lane & 15, quad = lane >> 4;
    const int m0 = blockIdx.y * 128, n0 = blockIdx.x * 128;
    const int kz0 = blockIdx.z * KS;
    const int r0 = lane >> 2, c0 = (lane & 3) * 8;

    f4v acc[4][4] = {};

    for (int k0 = kz0; k0 < kz0 + KS; k0 += 32) {
#pragma unroll
        for (int j = 0; j < 2; ++j) {
            int chunk = w * 2 + j;
            int row   = chunk * 16 + r0;
            gld16(&A[(size_t)(m0 + row) * K + k0 + c0], (char*)As + chunk * 1024);
            gld16(&B[(size_t)(n0 + row) * K + k0 + c0], (char*)Bs + chunk * 1024);
        }
        __syncthreads();
        bf8v af[4], bfv[4];
#pragma unroll
        for (int t = 0; t < 4; ++t) {
            af[t]  = *reinterpret_cast<const bf8v*>(&As[(wm * 64 + t * 16 + mm) * 32 + quad * 8]);
            bfv[t] = *reinterpret_cast<const bf8v*>(&Bs[(wn * 64 + t * 16 + mm) * 32 + quad * 8]);
        }
#pragma unroll
        for (int mt = 0; mt < 4; ++mt)
#pragma unroll
            for (int nt = 0; nt < 4; ++nt)
                acc[mt][nt] = __builtin_amdgcn_mfma_f32_16x16x32_bf16(af[mt], bfv[nt], acc[mt][nt], 0, 0, 0);
        __syncthreads();
    }
    __bf16* Pz = P + (size_t)blockIdx.z * M * N;
#pragma unroll
    for (int mt = 0; mt < 4; ++mt)
#pragma unroll
        for (int nt = 0; nt < 4; ++nt)
#pragma unroll
            for (int r = 0; r < 4; ++r)
                Pz[(size_t)(m0 + wm * 64 + mt * 16 + quad * 4 + r) * N
                   + n0 + wn * 64 + nt * 16 + mm] = (__bf16)acc[mt][nt][r];
}

// ---- sum 4 bf16 partials -> fp32 out -----------------------------------
__global__ __launch_bounds__(256)
void add4(const __bf16* __restrict__ P, float* __restrict__ out, int n4)
{
    int i = blockIdx.x * 256 + threadIdx.x;
    if (i >= n4) return;
    float4 s = {0.f, 0.f, 0.f, 0.f};
#pragma unroll
    for (int z = 0; z < 4; ++z) {
        bf4v v = *reinterpret_cast<const bf4v*>(P + (size_t)z * n4 * 4 + (size_t)i * 4);
        s.x += (float)v[0]; s.y += (float)v[1]; s.z += (float)v[2]; s.w += (float)v[3];
    }
    *reinterpret_cast<float4*>(out + (size_t)i * 4) = s;
}

// ---- norm_rope: sum 2 GEMM partials (q,k heads), RMSNorm + RoPE --------
__global__ __launch_bounds__(64)
void norm_rope(__bf16* __restrict__ qkv /* p0, in place */,
               const __bf16* __restrict__ p1,
               const float* __restrict__ qw, const float* __restrict__ kw)
{
    const int s = blockIdx.x, hh = blockIdx.y, l = threadIdx.x;
    const float* wn; float scale; int off;
    if (hh < NH) { off = hh * HD;               wn = qw; scale = 0.08838834764831845f; }
    else         { off = 2048 + (hh - NH) * HD; wn = kw; scale = 1.0f; }
    __bf16* p = qkv + (size_t)s * QS + off;
    const __bf16* q1 = p1 + (size_t)s * QS + off;
    float x0 = (float)p[l]      + (float)q1[l];
    float x1 = (float)p[l + 64] + (float)q1[l + 64];
    float ss = x0 * x0 + x1 * x1;
#pragma unroll
    for (int o = 32; o; o >>= 1) ss += __shfl_xor(ss, o);
    float inv = rsqrtf(ss * (1.0f / 128.0f) + 1e-6f);
    x0 *= inv * wn[l];
    x1 *= inv * wn[l + 64];
    float invf = exp2f(-(float)l * (13.287712379549449f / 64.0f));
    float ang  = (float)s * invf;
    float c, sn;
    sincosf(ang, &sn, &c);
    p[l]      = (__bf16)((x0 * c - x1 * sn) * scale);
    p[l + 64] = (__bf16)((x1 * c + x0 * sn) * scale);
}

// ---- pack K tiles: per (kh,kt) a 16 KB image == desired LDS image ------
__global__ __launch_bounds__(256)
void pack_k(const __bf16* __restrict__ qkv, __bf16* __restrict__ Kt)
{
    const int kt = blockIdx.x, kh = blockIdx.y, t = threadIdx.x;
    char* tile = (char*)Kt + ((size_t)(kh * 32 + kt)) * 16384;
    const __bf16* src = qkv + 2048 + kh * HD;
#pragma unroll
    for (int i = 0; i < 4; ++i) {
        int cid = t * 4 + i;
        int key = cid >> 4, pc = cid & 15;
        int c = pc ^ (key & 15);
        bf8v v = *reinterpret_cast<const bf8v*>(src + (size_t)(kt * 64 + key) * QS + c * 8);
        *reinterpret_cast<bf8v*>(tile + cid * 16) = v;
    }
}

// ---- pack V tiles transposed; V = p0 + p1 (v skips norm_rope) ----------
__global__ __launch_bounds__(256)
void pack_v(const __bf16* __restrict__ qkv0, const __bf16* __restrict__ qkv1,
            __bf16* __restrict__ Vt)
{
    const int kt = blockIdx.x, kh = blockIdx.y, t = threadIdx.x;
    char* tile = (char*)Vt + ((size_t)(kh * 32 + kt)) * 16384;
    const __bf16* s0 = qkv0 + 2560 + kh * HD;
    const __bf16* s1 = qkv1 + 2560 + kh * HD;
#pragma unroll
    for (int i = 0; i < 4; ++i) {
        int cid = t * 4 + i;
        int d = cid >> 3, kcp = cid & 7;
        int kc = kcp ^ (d & 7);
        size_t base = (size_t)(kt * 64 + kc * 8) * QS + d;
        __bf16 tmp[8];
#pragma unroll
        for (int j = 0; j < 8; ++j)
            tmp[j] = (__bf16)((float)s0[base + (size_t)j * QS] +
                              (float)s1[base + (size_t)j * QS]);
        *reinterpret_cast<bf8v*>(tile + cid * 16) = *reinterpret_cast<bf8v*>(tmp);
    }
}

// ---- split-K MFMA flash attention, static-max softmax ------------------
// 512 thr = 8 waves = 2 query-heads sharing one staged K/V tile (GQA reuse):
// waves 0-3 -> head A rows 0..63, waves 4-7 -> head B rows 0..63.
// LDS 48 KB -> 3 blocks/CU; tile-stages and barriers halve vs 1-head blocks.
__global__ __launch_bounds__(512, 6)
void attn_split(const __bf16* __restrict__ qkv,
                const __bf16* __restrict__ Kt, const __bf16* __restrict__ Vt,
                __bf16* __restrict__ Op, float* __restrict__ Lp)
{
    __shared__ char Ks[16384];
    __shared__ char Vs[16384];
    __shared__ char Ps[8][2048];

    const int c = blockIdx.x, qt = 31 - blockIdx.y;
    if (c * 8 > qt) return;
    const int kh = blockIdx.z >> 1, hp = blockIdx.z & 1;
    const int kend = min(qt, c * 8 + 7);
    const int tid = threadIdx.x, lane = tid & 63, w = tid >> 6;
    const int g = w >> 2, w4 = w & 3;          // head-sub, row-group
    const int h = kh * 4 + hp * 2 + g;
    const int mm = lane & 15, quad = lane >> 4;

    bf8v aq[4];
    const __bf16* qbase = qkv + (size_t)(qt * 64 + w4 * 16 + mm) * QS + h * HD;
#pragma unroll
    for (int ks = 0; ks < 4; ++ks)
        aq[ks] = *reinterpret_cast<const bf8v*>(qbase + ks * 32 + quad * 8);

    float lp[4] = {};
    f4v oacc[8] = {};

    for (int kt = c * 8; kt <= kend; ++kt) {
        __syncthreads();
        const char* ktile = (const char*)Kt + ((size_t)(kh * 32 + kt)) * 16384;
        const char* vtile = (const char*)Vt + ((size_t)(kh * 32 + kt)) * 16384;
#pragma unroll
        for (int j = 0; j < 2; ++j) {
            int chunk = w * 2 + j;             // 16 chunks each over 8 waves
            gld16(ktile + chunk * 1024 + lane * 16, Ks + chunk * 1024);
            gld16(vtile + chunk * 1024 + lane * 16, Vs + chunk * 1024);
        }
        __syncthreads();

        f4v s[4] = {};
#pragma unroll
        for (int ks = 0; ks < 4; ++ks)
#pragma unroll
            for (int c16 = 0; c16 < 4; ++c16) {
                bf8v b = *reinterpret_cast<const bf8v*>(
                    Ks + (c16 * 16 + mm) * 256 + (((ks * 4 + quad) ^ mm) << 4));
                s[c16] = __builtin_amdgcn_mfma_f32_16x16x32_bf16(aq[ks], b, s[c16], 0, 0, 0);
            }
        if (kt == qt) {
#pragma unroll
            for (int c16 = 0; c16 < 4; ++c16)
#pragma unroll
                for (int r = 0; r < 4; ++r)
                    if (c16 * 16 + mm > w4 * 16 + quad * 4 + r)
                        s[c16][r] = -__builtin_inff();
        }
        float pr[4][4];
#pragma unroll
        for (int c16 = 0; c16 < 4; ++c16)
#pragma unroll
            for (int r = 0; r < 4; ++r) {
                pr[c16][r] = __expf(s[c16][r]);
                lp[r] += pr[c16][r];
            }
#pragma unroll
        for (int c16 = 0; c16 < 4; ++c16)
#pragma unroll
            for (int r = 0; r < 4; ++r) {
                float mine  = pr[c16][r];
                float other = __shfl_xor(mine, 1);
                if ((mm & 1) == 0) {
                    int roww = quad * 4 + r;
                    int cc   = c16 * 2 + (mm >> 3);
                    *reinterpret_cast<bf2v*>(
                        &Ps[w][roww * 128 + ((cc ^ (roww & 7)) << 4) + (mm & 7) * 2]) =
                        bf2v{ (__bf16)mine, (__bf16)other };
                }
            }
        bf8v pa[2];
#pragma unroll
        for (int kb = 0; kb < 2; ++kb)
            pa[kb] = *reinterpret_cast<const bf8v*>(
                &Ps[w][mm * 128 + (((kb * 4 + quad) ^ (mm & 7)) << 4)]);
#pragma unroll
        for (int nb = 0; nb < 8; ++nb) {
            int d = nb * 16 + mm;
#pragma unroll
            for (int kb = 0; kb < 2; ++kb) {
                bf8v bv = *reinterpret_cast<const bf8v*>(
                    Vs + d * 128 + (((kb * 4 + quad) ^ (d & 7)) << 4));
                oacc[nb] = __builtin_amdgcn_mfma_f32_16x16x32_bf16(pa[kb], bv, oacc[nb], 0, 0, 0);
            }
        }
    }
#pragma unroll
    for (int off = 1; off < 16; off <<= 1)
#pragma unroll
        for (int r = 0; r < 4; ++r) lp[r] += __shfl_xor(lp[r], off);
#pragma unroll
    for (int r = 0; r < 4; ++r) {
        int row = qt * 64 + w4 * 16 + quad * 4 + r;
        size_t obase = ((size_t)(c * 16 + h) * SEQ + row) * HD;
#pragma unroll
        for (int nb = 0; nb < 8; ++nb)
            Op[obase + nb * 16 + mm] = (__bf16)oacc[nb][r];
        if (mm == 0)
            Lp[(size_t)(c * 16 + h) * SEQ + row] = lp[r];
    }
}

// ---- combine split-K partials -> ab (bf16 [row][h*128+d]) --------------
__global__ __launch_bounds__(64)
void combine(const __bf16* __restrict__ Op, const float* __restrict__ Lp,
             __bf16* __restrict__ ab)
{
    const int row = blockIdx.x, h = blockIdx.y, l = threadIdx.x;
    const int nch = (row >> 9) + 1;
    float L = 0.f, a0 = 0.f, a1 = 0.f;
    for (int c = 0; c < nch; ++c) {
        L += Lp[(size_t)(c * 16 + h) * SEQ + row];
        bf2v p = *reinterpret_cast<const bf2v*>(
            Op + ((size_t)(c * 16 + h) * SEQ + row) * HD + 2 * l);
        a0 += (float)p[0];
        a1 += (float)p[1];
    }
    float inv = 1.f / L;
    *reinterpret_cast<bf2v*>(ab + (size_t)row * (NH * HD) + h * HD + 2 * l) =
        bf2v{ (__bf16)(a0 * inv), (__bf16)(a1 * inv) };
}

extern "C" void kernel_launch(void* const* d_in, const int* in_sizes, int n_in,
                              void* d_out, int out_size, void* d_ws, size_t ws_size,
                              hipStream_t stream)
{
    const float* hs  = (const float*)d_in[0];
    const float* mu  = (const float*)d_in[1];
    const float* wq  = (const float*)d_in[2];
    const float* wk  = (const float*)d_in[3];
    const float* wv  = (const float*)d_in[4];
    const float* wo  = (const float*)d_in[5];
    const float* wmq = (const float*)d_in[6];
    const float* wmk = (const float*)d_in[7];
    const float* wmv = (const float*)d_in[8];
    const float* qw  = (const float*)d_in[9];
    const float* kw  = (const float*)d_in[10];
    float* out = (float*)d_out;

    char* ws = (char*)d_ws;
    // phase 1 (projection):
    __bf16* Wcat = (__bf16*)(ws + 0);          // [3072,4096] 25.2 MB
    __bf16* Acat = (__bf16*)(ws + 25165824);   // [2048,4096] 16.8 MB
    __bf16* Wo   = (__bf16*)(ws + 41943040);   // [2048,2048]  8.4 MB
    __bf16* qkvp = (__bf16*)(ws + 50331648);   // 2x[2048,3072] bf16 partials
    __bf16* ab   = (__bf16*)(ws + 75497472);   // [2048,2048] bf16, peak 83.9 MB
    // phase 2 aliases (Wcat/Acat dead after QKV GEMM):
    __bf16* Ktl  = (__bf16*)(ws + 0);          // 2 MB
    __bf16* Vtl  = (__bf16*)(ws + 2097152);    // 2 MB
    __bf16* Opart= (__bf16*)(ws + 4194304);    // 32 MB (ends 37.7 MB)
    float*  Lpart= (float*) (ws + 37748736);   // 0.5 MB
    // phase 3 alias (attn scratch dead after combine):
    __bf16* outp = (__bf16*)(ws + 0);          // 4x[2048,2048] bf16 = 33.6 MB

    cvt_cat2<<<dim3((2048 * 1024 + 255) / 256), 256, 0, stream>>>(Acat, hs, mu, 2048, 512);
    cvt_cat2<<<dim3((2048 * 1024 + 255) / 256), 256, 0, stream>>>(Wcat, wq, wmq, 2048, 512);
    cvt_cat2<<<dim3((512 * 1024 + 255) / 256), 256, 0, stream>>>(Wcat + (size_t)2048 * 4096, wk, wmk, 512, 512);
    cvt_cat2<<<dim3((512 * 1024 + 255) / 256), 256, 0, stream>>>(Wcat + (size_t)2560 * 4096, wv, wmv, 512, 512);
    cvt<<<dim3((1024 * 1024 + 255) / 256), 256, 0, stream>>>(Wo, wo, 1024 * 1024);

    // QKV projection, split-K=2: grid 24x16x2 = 768 blocks = 3/CU
    gemm_nt_sp<<<dim3(QS / 128, SEQ / 128, 2), 256, 0, stream>>>(Acat, Wcat, qkvp, SEQ, QS, 2 * HID_DIM, HID_DIM);
    norm_rope<<<dim3(SEQ, NH + NKV), dim3(64), 0, stream>>>(qkvp, qkvp + (size_t)SEQ * QS, qw, kw);
    pack_k<<<dim3(32, NKV), 256, 0, stream>>>(qkvp, Ktl);
    pack_v<<<dim3(32, NKV), 256, 0, stream>>>(qkvp, qkvp + (size_t)SEQ * QS, Vtl);
    // attention: 512-thr blocks, 2 heads each; grid (c, qt desc, kh*2)
    attn_split<<<dim3(4, 32, 8), 512, 0, stream>>>(qkvp, Ktl, Vtl, Opart, Lpart);
    combine<<<dim3(SEQ, NH), 64, 0, stream>>>(Opart, Lpart, ab);
    // output projection, split-K=4: grid 16x16x4 = 1024 blocks = 4/CU
    gemm_nt_sp<<<dim3(HID_DIM / 128, SEQ / 128, 4), 256, 0, stream>>>(ab, Wo, outp, SEQ, HID_DIM, NH * HD, 512);
    add4<<<dim3((1024 * 1024 + 255) / 256), 256, 0, stream>>>(outp, out, 1024 * 1024);
}

// Round 10
// 380.062 us; speedup vs baseline: 1.1470x; 1.1470x over previous
//
#include <hip/hip_runtime.h>
#include <math.h>

#define SEQ 2048
#define HID_DIM 2048
#define NH 16
#define NKV 4
#define HD 128
#define QS 3072   // fused qkv row stride (bf16): [q 2048 | k 512 | v 512]

typedef float  f4v  __attribute__((ext_vector_type(4)));
typedef __bf16 bf8v __attribute__((ext_vector_type(8)));
typedef __bf16 bf4v __attribute__((ext_vector_type(4)));
typedef __bf16 bf2v __attribute__((ext_vector_type(2)));

typedef __attribute__((address_space(1))) const void* gvp;
typedef __attribute__((address_space(3))) void*       svp;

__device__ __forceinline__ void gld16(const void* g, void* lds_wave_base) {
    __builtin_amdgcn_global_load_lds((gvp)g, (svp)lds_wave_base, 16, 0, 0);
}

// ---- fp32 -> bf16 converts ---------------------------------------------
__global__ __launch_bounds__(256)
void cvt_cat2(__bf16* __restrict__ dst, const float* __restrict__ s0,
              const float* __restrict__ s1, int rows, int kq)
{
    int i = blockIdx.x * 256 + threadIdx.x;
    if (i >= rows * kq * 2) return;
    int row = i / (2 * kq), c = i - row * 2 * kq;
    const float* s = (c < kq) ? s0 + ((size_t)row * kq + c) * 4
                              : s1 + ((size_t)row * kq + (c - kq)) * 4;
    float4 v = *reinterpret_cast<const float4*>(s);
    *reinterpret_cast<bf4v*>(dst + ((size_t)row * 2 * kq + c) * 4) =
        bf4v{ (__bf16)v.x, (__bf16)v.y, (__bf16)v.z, (__bf16)v.w };
}

__global__ __launch_bounds__(256)
void cvt(__bf16* __restrict__ dst, const float* __restrict__ src, int n4)
{
    int i = blockIdx.x * 256 + threadIdx.x;
    if (i >= n4) return;
    float4 v = *reinterpret_cast<const float4*>(src + (size_t)i * 4);
    *reinterpret_cast<bf4v*>(dst + (size_t)i * 4) =
        bf4v{ (__bf16)v.x, (__bf16)v.y, (__bf16)v.z, (__bf16)v.w };
}

// ---- split-K NT GEMM, 128x128 tile, bf16 partials (uneven K ok) --------
__global__ __launch_bounds__(256)
void gemm_nt_sp(const __bf16* __restrict__ A, const __bf16* __restrict__ B,
                __bf16* __restrict__ P, int M, int N, int K, int KS)
{
    __shared__ __bf16 As[128 * 32];
    __shared__ __bf16 Bs[128 * 32];
    const int tid = threadIdx.x, lane = tid & 63, w = tid >> 6;
    const int wm = w >> 1, wn = w & 1;
    const int mm = lane & 15, quad = lane >> 4;
    const int m0 = blockIdx.y * 128, n0 = blockIdx.x * 128;
    const int kz0 = blockIdx.z * KS;
    const int kEnd = min(kz0 + KS, K);
    const int r0 = lane >> 2, c0 = (lane & 3) * 8;

    f4v acc[4][4] = {};

    for (int k0 = kz0; k0 < kEnd; k0 += 32) {
#pragma unroll
        for (int j = 0; j < 2; ++j) {
            int chunk = w * 2 + j;
            int row   = chunk * 16 + r0;
            gld16(&A[(size_t)(m0 + row) * K + k0 + c0], (char*)As + chunk * 1024);
            gld16(&B[(size_t)(n0 + row) * K + k0 + c0], (char*)Bs + chunk * 1024);
        }
        __syncthreads();
        bf8v af[4], bfv[4];
#pragma unroll
        for (int t = 0; t < 4; ++t) {
            af[t]  = *reinterpret_cast<const bf8v*>(&As[(wm * 64 + t * 16 + mm) * 32 + quad * 8]);
            bfv[t] = *reinterpret_cast<const bf8v*>(&Bs[(wn * 64 + t * 16 + mm) * 32 + quad * 8]);
        }
#pragma unroll
        for (int mt = 0; mt < 4; ++mt)
#pragma unroll
            for (int nt = 0; nt < 4; ++nt)
                acc[mt][nt] = __builtin_amdgcn_mfma_f32_16x16x32_bf16(af[mt], bfv[nt], acc[mt][nt], 0, 0, 0);
        __syncthreads();
    }
    __bf16* Pz = P + (size_t)blockIdx.z * M * N;
#pragma unroll
    for (int mt = 0; mt < 4; ++mt)
#pragma unroll
        for (int nt = 0; nt < 4; ++nt)
#pragma unroll
            for (int r = 0; r < 4; ++r)
                Pz[(size_t)(m0 + wm * 64 + mt * 16 + quad * 4 + r) * N
                   + n0 + wn * 64 + nt * 16 + mm] = (__bf16)acc[mt][nt][r];
}

// ---- sum 4 bf16 partials -> fp32 out -----------------------------------
__global__ __launch_bounds__(256)
void add4(const __bf16* __restrict__ P, float* __restrict__ out, int n4)
{
    int i = blockIdx.x * 256 + threadIdx.x;
    if (i >= n4) return;
    float4 s = {0.f, 0.f, 0.f, 0.f};
#pragma unroll
    for (int z = 0; z < 4; ++z) {
        bf4v v = *reinterpret_cast<const bf4v*>(P + (size_t)z * n4 * 4 + (size_t)i * 4);
        s.x += (float)v[0]; s.y += (float)v[1]; s.z += (float)v[2]; s.w += (float)v[3];
    }
    *reinterpret_cast<float4*>(out + (size_t)i * 4) = s;
}

// ---- norm_rope: sum 3 GEMM partials (q,k heads), RMSNorm + RoPE --------
__global__ __launch_bounds__(64)
void norm_rope(__bf16* __restrict__ qkv /* p0, in place */,
               const __bf16* __restrict__ p1, const __bf16* __restrict__ p2,
               const float* __restrict__ qw, const float* __restrict__ kw)
{
    const int s = blockIdx.x, hh = blockIdx.y, l = threadIdx.x;
    const float* wn; float scale; int off;
    if (hh < NH) { off = hh * HD;               wn = qw; scale = 0.08838834764831845f; }
    else         { off = 2048 + (hh - NH) * HD; wn = kw; scale = 1.0f; }
    __bf16* p = qkv + (size_t)s * QS + off;
    const __bf16* q1 = p1 + (size_t)s * QS + off;
    const __bf16* q2 = p2 + (size_t)s * QS + off;
    float x0 = (float)p[l]      + (float)q1[l]      + (float)q2[l];
    float x1 = (float)p[l + 64] + (float)q1[l + 64] + (float)q2[l + 64];
    float ss = x0 * x0 + x1 * x1;
#pragma unroll
    for (int o = 32; o; o >>= 1) ss += __shfl_xor(ss, o);
    float inv = rsqrtf(ss * (1.0f / 128.0f) + 1e-6f);
    x0 *= inv * wn[l];
    x1 *= inv * wn[l + 64];
    float invf = exp2f(-(float)l * (13.287712379549449f / 64.0f));
    float ang  = (float)s * invf;
    float c, sn;
    sincosf(ang, &sn, &c);
    p[l]      = (__bf16)((x0 * c - x1 * sn) * scale);
    p[l + 64] = (__bf16)((x1 * c + x0 * sn) * scale);
}

// ---- pack K tiles: per (kh,kt) a 16 KB image == desired LDS image ------
__global__ __launch_bounds__(256)
void pack_k(const __bf16* __restrict__ qkv, __bf16* __restrict__ Kt)
{
    const int kt = blockIdx.x, kh = blockIdx.y, t = threadIdx.x;
    char* tile = (char*)Kt + ((size_t)(kh * 32 + kt)) * 16384;
    const __bf16* src = qkv + 2048 + kh * HD;
#pragma unroll
    for (int i = 0; i < 4; ++i) {
        int cid = t * 4 + i;
        int key = cid >> 4, pc = cid & 15;
        int c = pc ^ (key & 15);
        bf8v v = *reinterpret_cast<const bf8v*>(src + (size_t)(kt * 64 + key) * QS + c * 8);
        *reinterpret_cast<bf8v*>(tile + cid * 16) = v;
    }
}

// ---- pack V tiles transposed; V = p0+p1+p2 (v skips norm_rope) ---------
__global__ __launch_bounds__(256)
void pack_v(const __bf16* __restrict__ q0, const __bf16* __restrict__ q1,
            const __bf16* __restrict__ q2, __bf16* __restrict__ Vt)
{
    const int kt = blockIdx.x, kh = blockIdx.y, t = threadIdx.x;
    char* tile = (char*)Vt + ((size_t)(kh * 32 + kt)) * 16384;
    const __bf16* s0 = q0 + 2560 + kh * HD;
    const __bf16* s1 = q1 + 2560 + kh * HD;
    const __bf16* s2 = q2 + 2560 + kh * HD;
#pragma unroll
    for (int i = 0; i < 4; ++i) {
        int cid = t * 4 + i;
        int d = cid >> 3, kcp = cid & 7;
        int kc = kcp ^ (d & 7);
        size_t base = (size_t)(kt * 64 + kc * 8) * QS + d;
        __bf16 tmp[8];
#pragma unroll
        for (int j = 0; j < 8; ++j)
            tmp[j] = (__bf16)((float)s0[base + (size_t)j * QS] +
                              (float)s1[base + (size_t)j * QS] +
                              (float)s2[base + (size_t)j * QS]);
        *reinterpret_cast<bf8v*>(tile + cid * 16) = *reinterpret_cast<bf8v*>(tmp);
    }
}

// ---- split-K MFMA flash attention, static-max softmax (round-8 cfg) ----
__global__ __launch_bounds__(256)
void attn_split(const __bf16* __restrict__ qkv,
                const __bf16* __restrict__ Kt, const __bf16* __restrict__ Vt,
                __bf16* __restrict__ Op, float* __restrict__ Lp)
{
    __shared__ char Ks[16384];
    __shared__ char Vs[16384];
    __shared__ char Ps[4][2048];

    const int c = blockIdx.x, qt = 31 - blockIdx.y, h = blockIdx.z;
    if (c * 8 > qt) return;
    const int kend = min(qt, c * 8 + 7);
    const int tid = threadIdx.x, lane = tid & 63, w = tid >> 6;
    const int mm = lane & 15, quad = lane >> 4;
    const int kh = h >> 2;

    bf8v aq[4];
    const __bf16* qbase = qkv + (size_t)(qt * 64 + w * 16 + mm) * QS + h * HD;
#pragma unroll
    for (int ks = 0; ks < 4; ++ks)
        aq[ks] = *reinterpret_cast<const bf8v*>(qbase + ks * 32 + quad * 8);

    float lp[4] = {};
    f4v oacc[8] = {};

    for (int kt = c * 8; kt <= kend; ++kt) {
        __syncthreads();
        const char* ktile = (const char*)Kt + ((size_t)(kh * 32 + kt)) * 16384;
        const char* vtile = (const char*)Vt + ((size_t)(kh * 32 + kt)) * 16384;
#pragma unroll
        for (int j = 0; j < 4; ++j) {
            int chunk = w * 4 + j;
            gld16(ktile + chunk * 1024 + lane * 16, Ks + chunk * 1024);
            gld16(vtile + chunk * 1024 + lane * 16, Vs + chunk * 1024);
        }
        __syncthreads();

        f4v s[4] = {};
#pragma unroll
        for (int ks = 0; ks < 4; ++ks)
#pragma unroll
            for (int c16 = 0; c16 < 4; ++c16) {
                bf8v b = *reinterpret_cast<const bf8v*>(
                    Ks + (c16 * 16 + mm) * 256 + (((ks * 4 + quad) ^ mm) << 4));
                s[c16] = __builtin_amdgcn_mfma_f32_16x16x32_bf16(aq[ks], b, s[c16], 0, 0, 0);
            }
        if (kt == qt) {
#pragma unroll
            for (int c16 = 0; c16 < 4; ++c16)
#pragma unroll
                for (int r = 0; r < 4; ++r)
                    if (c16 * 16 + mm > w * 16 + quad * 4 + r)
                        s[c16][r] = -__builtin_inff();
        }
        float pr[4][4];
#pragma unroll
        for (int c16 = 0; c16 < 4; ++c16)
#pragma unroll
            for (int r = 0; r < 4; ++r) {
                pr[c16][r] = __expf(s[c16][r]);
                lp[r] += pr[c16][r];
            }
#pragma unroll
        for (int c16 = 0; c16 < 4; ++c16)
#pragma unroll
            for (int r = 0; r < 4; ++r) {
                float mine  = pr[c16][r];
                float other = __shfl_xor(mine, 1);
                if ((mm & 1) == 0) {
                    int roww = quad * 4 + r;
                    int cc   = c16 * 2 + (mm >> 3);
                    *reinterpret_cast<bf2v*>(
                        &Ps[w][roww * 128 + ((cc ^ (roww & 7)) << 4) + (mm & 7) * 2]) =
                        bf2v{ (__bf16)mine, (__bf16)other };
                }
            }
        bf8v pa[2];
#pragma unroll
        for (int kb = 0; kb < 2; ++kb)
            pa[kb] = *reinterpret_cast<const bf8v*>(
                &Ps[w][mm * 128 + (((kb * 4 + quad) ^ (mm & 7)) << 4)]);
#pragma unroll
        for (int nb = 0; nb < 8; ++nb) {
            int d = nb * 16 + mm;
#pragma unroll
            for (int kb = 0; kb < 2; ++kb) {
                bf8v bv = *reinterpret_cast<const bf8v*>(
                    Vs + d * 128 + (((kb * 4 + quad) ^ (d & 7)) << 4));
                oacc[nb] = __builtin_amdgcn_mfma_f32_16x16x32_bf16(pa[kb], bv, oacc[nb], 0, 0, 0);
            }
        }
    }
#pragma unroll
    for (int off = 1; off < 16; off <<= 1)
#pragma unroll
        for (int r = 0; r < 4; ++r) lp[r] += __shfl_xor(lp[r], off);
#pragma unroll
    for (int r = 0; r < 4; ++r) {
        int row = qt * 64 + w * 16 + quad * 4 + r;
        size_t obase = ((size_t)(c * 16 + h) * SEQ + row) * HD;
#pragma unroll
        for (int nb = 0; nb < 8; ++nb)
            Op[obase + nb * 16 + mm] = (__bf16)oacc[nb][r];
        if (mm == 0)
            Lp[(size_t)(c * 16 + h) * SEQ + row] = lp[r];
    }
}

// ---- combine split-K partials -> ab (bf16 [row][h*128+d]) --------------
__global__ __launch_bounds__(64)
void combine(const __bf16* __restrict__ Op, const float* __restrict__ Lp,
             __bf16* __restrict__ ab)
{
    const int row = blockIdx.x, h = blockIdx.y, l = threadIdx.x;
    const int nch = (row >> 9) + 1;
    float L = 0.f, a0 = 0.f, a1 = 0.f;
    for (int c = 0; c < nch; ++c) {
        L += Lp[(size_t)(c * 16 + h) * SEQ + row];
        bf2v p = *reinterpret_cast<const bf2v*>(
            Op + ((size_t)(c * 16 + h) * SEQ + row) * HD + 2 * l);
        a0 += (float)p[0];
        a1 += (float)p[1];
    }
    float inv = 1.f / L;
    *reinterpret_cast<bf2v*>(ab + (size_t)row * (NH * HD) + h * HD + 2 * l) =
        bf2v{ (__bf16)(a0 * inv), (__bf16)(a1 * inv) };
}

extern "C" void kernel_launch(void* const* d_in, const int* in_sizes, int n_in,
                              void* d_out, int out_size, void* d_ws, size_t ws_size,
                              hipStream_t stream)
{
    const float* hs  = (const float*)d_in[0];
    const float* mu  = (const float*)d_in[1];
    const float* wq  = (const float*)d_in[2];
    const float* wk  = (const float*)d_in[3];
    const float* wv  = (const float*)d_in[4];
    const float* wo  = (const float*)d_in[5];
    const float* wmq = (const float*)d_in[6];
    const float* wmk = (const float*)d_in[7];
    const float* wmv = (const float*)d_in[8];
    const float* qw  = (const float*)d_in[9];
    const float* kw  = (const float*)d_in[10];
    float* out = (float*)d_out;

    char* ws = (char*)d_ws;
    // phase 1: Wcat [0,25.2M), Acat [25.2,41.9M), qkvp 3x12.58M [41.9,79.7M)
    __bf16* Wcat = (__bf16*)(ws + 0);
    __bf16* Acat = (__bf16*)(ws + 25165824);
    __bf16* qkvp = (__bf16*)(ws + 41943040);
    const size_t QKVN = (size_t)SEQ * QS;   // 6291456 elems per partial
    // phase 2 aliases (Wcat/Acat dead after qkv gemm):
    __bf16* Ktl   = (__bf16*)(ws + 0);          // 2 MB
    __bf16* Vtl   = (__bf16*)(ws + 2097152);    // 2 MB
    __bf16* Opart = (__bf16*)(ws + 4194304);    // 33.55 MB -> ends 37.75M
    float*  Lpart = (float*) (ws + 37748736);   // 0.5 MB
    // Wo in dead qkvp[1] (after pack_v); ab in dead qkvp[2] (after combine prereqs)
    __bf16* Wo = (__bf16*)(ws + 54525952);      // 8.4 MB -> ends 62.9M
    __bf16* ab = (__bf16*)(ws + 67108864);      // 8.4 MB -> ends 75.5M
    // phase 3 alias: out partials over dead Ktl/Vtl/Opart
    __bf16* outp = (__bf16*)(ws + 0);           // 4 x 8.39 MB = 33.55 MB

    cvt_cat2<<<dim3((2048 * 1024 + 255) / 256), 256, 0, stream>>>(Acat, hs, mu, 2048, 512);
    cvt_cat2<<<dim3((2048 * 1024 + 255) / 256), 256, 0, stream>>>(Wcat, wq, wmq, 2048, 512);
    cvt_cat2<<<dim3((512 * 1024 + 255) / 256), 256, 0, stream>>>(Wcat + (size_t)2048 * 4096, wk, wmk, 512, 512);
    cvt_cat2<<<dim3((512 * 1024 + 255) / 256), 256, 0, stream>>>(Wcat + (size_t)2560 * 4096, wv, wmv, 512, 512);

    // QKV projection, split-K=3 (uneven 43/43/42 iters): 1152 blocks = 4.5/CU
    gemm_nt_sp<<<dim3(QS / 128, SEQ / 128, 3), 256, 0, stream>>>(Acat, Wcat, qkvp, SEQ, QS, 2 * HID_DIM, 1376);
    norm_rope<<<dim3(SEQ, NH + NKV), dim3(64), 0, stream>>>(qkvp, qkvp + QKVN, qkvp + 2 * QKVN, qw, kw);
    pack_k<<<dim3(32, NKV), 256, 0, stream>>>(qkvp, Ktl);
    pack_v<<<dim3(32, NKV), 256, 0, stream>>>(qkvp, qkvp + QKVN, qkvp + 2 * QKVN, Vtl);
    // Wo convert (into dead qkvp[1]) — must follow pack_v
    cvt<<<dim3((1024 * 1024 + 255) / 256), 256, 0, stream>>>(Wo, wo, 1024 * 1024);

    attn_split<<<dim3(4, 32, NH), 256, 0, stream>>>(qkvp, Ktl, Vtl, Opart, Lpart);
    combine<<<dim3(SEQ, NH), 64, 0, stream>>>(Opart, Lpart, ab);
    // output projection, split-K=4: 1024 blocks = 4/CU
    gemm_nt_sp<<<dim3(HID_DIM / 128, SEQ / 128, 4), 256, 0, stream>>>(ab, Wo, outp, SEQ, HID_DIM, NH * HD, 512);
    add4<<<dim3((1024 * 1024 + 255) / 256), 256, 0, stream>>>(outp, out, 1024 * 1024);
}

// Round 11
// 371.767 us; speedup vs baseline: 1.1726x; 1.0223x over previous
//
#include <hip/hip_runtime.h>
#include <math.h>

#define SEQ 2048
#define HID_DIM 2048
#define NH 16
#define NKV 4
#define HD 128
#define QS 3072   // fused qkv row stride (bf16): [q 2048 | k 512 | v 512]

typedef float  f4v  __attribute__((ext_vector_type(4)));
typedef __bf16 bf8v __attribute__((ext_vector_type(8)));
typedef __bf16 bf4v __attribute__((ext_vector_type(4)));
typedef __bf16 bf2v __attribute__((ext_vector_type(2)));

typedef __attribute__((address_space(1))) const void* gvp;
typedef __attribute__((address_space(3))) void*       svp;

__device__ __forceinline__ void gld16(const void* g, void* lds_wave_base) {
    __builtin_amdgcn_global_load_lds((gvp)g, (svp)lds_wave_base, 16, 0, 0);
}

// ---- one fused fp32->bf16 convert pass (all operands, 1 launch) --------
__device__ __forceinline__ void cat2_item(__bf16* dst, const float* s0,
                                          const float* s1, int i, int kq)
{
    int row = i / (2 * kq), c = i - row * 2 * kq;
    const float* s = (c < kq) ? s0 + ((size_t)row * kq + c) * 4
                              : s1 + ((size_t)row * kq + (c - kq)) * 4;
    float4 v = *reinterpret_cast<const float4*>(s);
    *reinterpret_cast<bf4v*>(dst + ((size_t)row * 2 * kq + c) * 4) =
        bf4v{ (__bf16)v.x, (__bf16)v.y, (__bf16)v.z, (__bf16)v.w };
}

__global__ __launch_bounds__(256)
void cvt_all(const float* __restrict__ hs, const float* __restrict__ mu,
             const float* __restrict__ wq, const float* __restrict__ wmq,
             const float* __restrict__ wk, const float* __restrict__ wmk,
             const float* __restrict__ wv, const float* __restrict__ wmv,
             const float* __restrict__ wo,
             __bf16* __restrict__ Acat, __bf16* __restrict__ Wcat,
             __bf16* __restrict__ Wo)
{
    int i = blockIdx.x * 256 + threadIdx.x;   // float4-group index
    if (i < 2097152)       cat2_item(Acat, hs, mu, i, 512);
    else if (i < 4194304)  cat2_item(Wcat, wq, wmq, i - 2097152, 512);
    else if (i < 4718592)  cat2_item(Wcat + (size_t)2048 * 4096, wk, wmk, i - 4194304, 512);
    else if (i < 5242880)  cat2_item(Wcat + (size_t)2560 * 4096, wv, wmv, i - 4718592, 512);
    else if (i < 6291456) {
        int j = i - 5242880;
        float4 v = *reinterpret_cast<const float4*>(wo + (size_t)j * 4);
        *reinterpret_cast<bf4v*>(Wo + (size_t)j * 4) =
            bf4v{ (__bf16)v.x, (__bf16)v.y, (__bf16)v.z, (__bf16)v.w };
    }
}

// ---- split-K NT GEMM, 128x128 tile, bf16 partials ----------------------
__global__ __launch_bounds__(256)
void gemm_nt_sp(const __bf16* __restrict__ A, const __bf16* __restrict__ B,
                __bf16* __restrict__ P, int M, int N, int K, int KS)
{
    __shared__ __bf16 As[128 * 32];
    __shared__ __bf16 Bs[128 * 32];
    const int tid = threadIdx.x, lane = tid & 63, w = tid >> 6;
    const int wm = w >> 1, wn = w & 1;
    const int mm = lane & 15, quad = lane >> 4;
    const int m0 = blockIdx.y * 128, n0 = blockIdx.x * 128;
    const int kz0 = blockIdx.z * KS;
    const int kEnd = min(kz0 + KS, K);
    const int r0 = lane >> 2, c0 = (lane & 3) * 8;

    f4v acc[4][4] = {};

    for (int k0 = kz0; k0 < kEnd; k0 += 32) {
#pragma unroll
        for (int j = 0; j < 2; ++j) {
            int chunk = w * 2 + j;
            int row   = chunk * 16 + r0;
            gld16(&A[(size_t)(m0 + row) * K + k0 + c0], (char*)As + chunk * 1024);
            gld16(&B[(size_t)(n0 + row) * K + k0 + c0], (char*)Bs + chunk * 1024);
        }
        __syncthreads();
        bf8v af[4], bfv[4];
#pragma unroll
        for (int t = 0; t < 4; ++t) {
            af[t]  = *reinterpret_cast<const bf8v*>(&As[(wm * 64 + t * 16 + mm) * 32 + quad * 8]);
            bfv[t] = *reinterpret_cast<const bf8v*>(&Bs[(wn * 64 + t * 16 + mm) * 32 + quad * 8]);
        }
#pragma unroll
        for (int mt = 0; mt < 4; ++mt)
#pragma unroll
            for (int nt = 0; nt < 4; ++nt)
                acc[mt][nt] = __builtin_amdgcn_mfma_f32_16x16x32_bf16(af[mt], bfv[nt], acc[mt][nt], 0, 0, 0);
        __syncthreads();
    }
    __bf16* Pz = P + (size_t)blockIdx.z * M * N;
#pragma unroll
    for (int mt = 0; mt < 4; ++mt)
#pragma unroll
        for (int nt = 0; nt < 4; ++nt)
#pragma unroll
            for (int r = 0; r < 4; ++r)
                Pz[(size_t)(m0 + wm * 64 + mt * 16 + quad * 4 + r) * N
                   + n0 + wn * 64 + nt * 16 + mm] = (__bf16)acc[mt][nt][r];
}

// ---- sum 4 bf16 partials -> fp32 out -----------------------------------
__global__ __launch_bounds__(256)
void add4(const __bf16* __restrict__ P, float* __restrict__ out, int n4)
{
    int i = blockIdx.x * 256 + threadIdx.x;
    if (i >= n4) return;
    float4 s = {0.f, 0.f, 0.f, 0.f};
#pragma unroll
    for (int z = 0; z < 4; ++z) {
        bf4v v = *reinterpret_cast<const bf4v*>(P + (size_t)z * n4 * 4 + (size_t)i * 4);
        s.x += (float)v[0]; s.y += (float)v[1]; s.z += (float)v[2]; s.w += (float)v[3];
    }
    *reinterpret_cast<float4*>(out + (size_t)i * 4) = s;
}

// ---- norm_rope: sum 2 GEMM partials (q,k heads), RMSNorm + RoPE --------
__global__ __launch_bounds__(64)
void norm_rope(__bf16* __restrict__ qkv /* p0, in place */,
               const __bf16* __restrict__ p1,
               const float* __restrict__ qw, const float* __restrict__ kw)
{
    const int s = blockIdx.x, hh = blockIdx.y, l = threadIdx.x;
    const float* wn; float scale; int off;
    if (hh < NH) { off = hh * HD;               wn = qw; scale = 0.08838834764831845f; }
    else         { off = 2048 + (hh - NH) * HD; wn = kw; scale = 1.0f; }
    __bf16* p = qkv + (size_t)s * QS + off;
    const __bf16* q1 = p1 + (size_t)s * QS + off;
    float x0 = (float)p[l]      + (float)q1[l];
    float x1 = (float)p[l + 64] + (float)q1[l + 64];
    float ss = x0 * x0 + x1 * x1;
#pragma unroll
    for (int o = 32; o; o >>= 1) ss += __shfl_xor(ss, o);
    float inv = rsqrtf(ss * (1.0f / 128.0f) + 1e-6f);
    x0 *= inv * wn[l];
    x1 *= inv * wn[l + 64];
    float invf = exp2f(-(float)l * (13.287712379549449f / 64.0f));
    float ang  = (float)s * invf;
    float c, sn;
    sincosf(ang, &sn, &c);
    p[l]      = (__bf16)((x0 * c - x1 * sn) * scale);
    p[l + 64] = (__bf16)((x1 * c + x0 * sn) * scale);
}

// ---- pack K tiles: per (kh,kt) a 16 KB image == desired LDS image ------
__global__ __launch_bounds__(256)
void pack_k(const __bf16* __restrict__ qkv, __bf16* __restrict__ Kt)
{
    const int kt = blockIdx.x, kh = blockIdx.y, t = threadIdx.x;
    char* tile = (char*)Kt + ((size_t)(kh * 32 + kt)) * 16384;
    const __bf16* src = qkv + 2048 + kh * HD;
#pragma unroll
    for (int i = 0; i < 4; ++i) {
        int cid = t * 4 + i;
        int key = cid >> 4, pc = cid & 15;
        int c = pc ^ (key & 15);
        bf8v v = *reinterpret_cast<const bf8v*>(src + (size_t)(kt * 64 + key) * QS + c * 8);
        *reinterpret_cast<bf8v*>(tile + cid * 16) = v;
    }
}

// ---- pack V tiles transposed; V = p0 + p1 (v skips norm_rope) ----------
__global__ __launch_bounds__(256)
void pack_v(const __bf16* __restrict__ qkv0, const __bf16* __restrict__ qkv1,
            __bf16* __restrict__ Vt)
{
    const int kt = blockIdx.x, kh = blockIdx.y, t = threadIdx.x;
    char* tile = (char*)Vt + ((size_t)(kh * 32 + kt)) * 16384;
    const __bf16* s0 = qkv0 + 2560 + kh * HD;
    const __bf16* s1 = qkv1 + 2560 + kh * HD;
#pragma unroll
    for (int i = 0; i < 4; ++i) {
        int cid = t * 4 + i;
        int d = cid >> 3, kcp = cid & 7;
        int kc = kcp ^ (d & 7);
        size_t base = (size_t)(kt * 64 + kc * 8) * QS + d;
        __bf16 tmp[8];
#pragma unroll
        for (int j = 0; j < 8; ++j)
            tmp[j] = (__bf16)((float)s0[base + (size_t)j * QS] +
                              (float)s1[base + (size_t)j * QS]);
        *reinterpret_cast<bf8v*>(tile + cid * 16) = *reinterpret_cast<bf8v*>(tmp);
    }
}

// ---- split-K MFMA flash attention, static-max softmax, DOUBLE-BUFFERED -
// Prefetch tile kt+1 into the alternate 16 KB K/V buffers before computing
// tile kt; the barrier's vmcnt(0) drain then lands after ~1.5k cyc of
// compute, hiding the staging latency. LDS 72 KB -> 2 blocks/CU.
__global__ __launch_bounds__(256)
void attn_split(const __bf16* __restrict__ qkv,
                const __bf16* __restrict__ Kt, const __bf16* __restrict__ Vt,
                __bf16* __restrict__ Op, float* __restrict__ Lp)
{
    __shared__ char Ks[2][16384];
    __shared__ char Vs[2][16384];
    __shared__ char Ps[4][2048];

    const int c = blockIdx.x, qt = 31 - blockIdx.y, h = blockIdx.z;
    if (c * 8 > qt) return;
    const int kbeg = c * 8, kend = min(qt, c * 8 + 7);
    const int tid = threadIdx.x, lane = tid & 63, w = tid >> 6;
    const int mm = lane & 15, quad = lane >> 4;
    const int kh = h >> 2;

    bf8v aq[4];
    const __bf16* qbase = qkv + (size_t)(qt * 64 + w * 16 + mm) * QS + h * HD;
#pragma unroll
    for (int ks = 0; ks < 4; ++ks)
        aq[ks] = *reinterpret_cast<const bf8v*>(qbase + ks * 32 + quad * 8);

    float lp[4] = {};
    f4v oacc[8] = {};

    // stage first tile into buffer 0
    {
        const char* ktile = (const char*)Kt + ((size_t)(kh * 32 + kbeg)) * 16384;
        const char* vtile = (const char*)Vt + ((size_t)(kh * 32 + kbeg)) * 16384;
#pragma unroll
        for (int j = 0; j < 4; ++j) {
            int chunk = w * 4 + j;
            gld16(ktile + chunk * 1024 + lane * 16, Ks[0] + chunk * 1024);
            gld16(vtile + chunk * 1024 + lane * 16, Vs[0] + chunk * 1024);
        }
    }
    int cur = 0;
    for (int kt = kbeg; kt <= kend; ++kt) {
        __syncthreads();   // publishes stage/prefetch of tile kt (vmcnt drain)
        if (kt < kend) {   // prefetch kt+1 into the other buffer
            const char* ktile = (const char*)Kt + ((size_t)(kh * 32 + kt + 1)) * 16384;
            const char* vtile = (const char*)Vt + ((size_t)(kh * 32 + kt + 1)) * 16384;
#pragma unroll
            for (int j = 0; j < 4; ++j) {
                int chunk = w * 4 + j;
                gld16(ktile + chunk * 1024 + lane * 16, Ks[cur ^ 1] + chunk * 1024);
                gld16(vtile + chunk * 1024 + lane * 16, Vs[cur ^ 1] + chunk * 1024);
            }
        }
        const char* KsC = Ks[cur];
        const char* VsC = Vs[cur];

        f4v s[4] = {};
#pragma unroll
        for (int ks = 0; ks < 4; ++ks)
#pragma unroll
            for (int c16 = 0; c16 < 4; ++c16) {
                bf8v b = *reinterpret_cast<const bf8v*>(
                    KsC + (c16 * 16 + mm) * 256 + (((ks * 4 + quad) ^ mm) << 4));
                s[c16] = __builtin_amdgcn_mfma_f32_16x16x32_bf16(aq[ks], b, s[c16], 0, 0, 0);
            }
        if (kt == qt) {
#pragma unroll
            for (int c16 = 0; c16 < 4; ++c16)
#pragma unroll
                for (int r = 0; r < 4; ++r)
                    if (c16 * 16 + mm > w * 16 + quad * 4 + r)
                        s[c16][r] = -__builtin_inff();
        }
        float pr[4][4];
#pragma unroll
        for (int c16 = 0; c16 < 4; ++c16)
#pragma unroll
            for (int r = 0; r < 4; ++r) {
                pr[c16][r] = __expf(s[c16][r]);
                lp[r] += pr[c16][r];
            }
#pragma unroll
        for (int c16 = 0; c16 < 4; ++c16)
#pragma unroll
            for (int r = 0; r < 4; ++r) {
                float mine  = pr[c16][r];
                float other = __shfl_xor(mine, 1);
                if ((mm & 1) == 0) {
                    int roww = quad * 4 + r;
                    int cc   = c16 * 2 + (mm >> 3);
                    *reinterpret_cast<bf2v*>(
                        &Ps[w][roww * 128 + ((cc ^ (roww & 7)) << 4) + (mm & 7) * 2]) =
                        bf2v{ (__bf16)mine, (__bf16)other };
                }
            }
        bf8v pa[2];
#pragma unroll
        for (int kb = 0; kb < 2; ++kb)
            pa[kb] = *reinterpret_cast<const bf8v*>(
                &Ps[w][mm * 128 + (((kb * 4 + quad) ^ (mm & 7)) << 4)]);
#pragma unroll
        for (int nb = 0; nb < 8; ++nb) {
            int d = nb * 16 + mm;
#pragma unroll
            for (int kb = 0; kb < 2; ++kb) {
                bf8v bv = *reinterpret_cast<const bf8v*>(
                    VsC + d * 128 + (((kb * 4 + quad) ^ (d & 7)) << 4));
                oacc[nb] = __builtin_amdgcn_mfma_f32_16x16x32_bf16(pa[kb], bv, oacc[nb], 0, 0, 0);
            }
        }
        cur ^= 1;
    }
#pragma unroll
    for (int off = 1; off < 16; off <<= 1)
#pragma unroll
        for (int r = 0; r < 4; ++r) lp[r] += __shfl_xor(lp[r], off);
#pragma unroll
    for (int r = 0; r < 4; ++r) {
        int row = qt * 64 + w * 16 + quad * 4 + r;
        size_t obase = ((size_t)(c * 16 + h) * SEQ + row) * HD;
#pragma unroll
        for (int nb = 0; nb < 8; ++nb)
            Op[obase + nb * 16 + mm] = (__bf16)oacc[nb][r];
        if (mm == 0)
            Lp[(size_t)(c * 16 + h) * SEQ + row] = lp[r];
    }
}

// ---- combine split-K partials -> ab (bf16 [row][h*128+d]) --------------
__global__ __launch_bounds__(64)
void combine(const __bf16* __restrict__ Op, const float* __restrict__ Lp,
             __bf16* __restrict__ ab)
{
    const int row = blockIdx.x, h = blockIdx.y, l = threadIdx.x;
    const int nch = (row >> 9) + 1;
    float L = 0.f, a0 = 0.f, a1 = 0.f;
    for (int c = 0; c < nch; ++c) {
        L += Lp[(size_t)(c * 16 + h) * SEQ + row];
        bf2v p = *reinterpret_cast<const bf2v*>(
            Op + ((size_t)(c * 16 + h) * SEQ + row) * HD + 2 * l);
        a0 += (float)p[0];
        a1 += (float)p[1];
    }
    float inv = 1.f / L;
    *reinterpret_cast<bf2v*>(ab + (size_t)row * (NH * HD) + h * HD + 2 * l) =
        bf2v{ (__bf16)(a0 * inv), (__bf16)(a1 * inv) };
}

extern "C" void kernel_launch(void* const* d_in, const int* in_sizes, int n_in,
                              void* d_out, int out_size, void* d_ws, size_t ws_size,
                              hipStream_t stream)
{
    const float* hs  = (const float*)d_in[0];
    const float* mu  = (const float*)d_in[1];
    const float* wq  = (const float*)d_in[2];
    const float* wk  = (const float*)d_in[3];
    const float* wv  = (const float*)d_in[4];
    const float* wo  = (const float*)d_in[5];
    const float* wmq = (const float*)d_in[6];
    const float* wmk = (const float*)d_in[7];
    const float* wmv = (const float*)d_in[8];
    const float* qw  = (const float*)d_in[9];
    const float* kw  = (const float*)d_in[10];
    float* out = (float*)d_out;

    char* ws = (char*)d_ws;
    // round-8 layout: phase 1 (projection)
    __bf16* Wcat = (__bf16*)(ws + 0);          // [3072,4096] 25.2 MB
    __bf16* Acat = (__bf16*)(ws + 25165824);   // [2048,4096] 16.8 MB
    __bf16* Wo   = (__bf16*)(ws + 41943040);   // [2048,2048]  8.4 MB (persists)
    __bf16* qkvp = (__bf16*)(ws + 50331648);   // 2x[2048,3072] bf16 partials
    __bf16* ab   = (__bf16*)(ws + 75497472);   // [2048,2048] bf16, peak 83.9 MB
    const size_t QKVN = (size_t)SEQ * QS;
    // phase 2 aliases (Wcat/Acat dead after QKV GEMM):
    __bf16* Ktl  = (__bf16*)(ws + 0);          // 2 MB
    __bf16* Vtl  = (__bf16*)(ws + 2097152);    // 2 MB
    __bf16* Opart= (__bf16*)(ws + 4194304);    // 33.55 MB (ends 37.75M < Wo)
    float*  Lpart= (float*) (ws + 37748736);   // 0.5 MB
    // phase 3 alias (attn scratch dead after combine):
    __bf16* outp = (__bf16*)(ws + 0);          // 4x8.39 MB = 33.55 MB < Wo

    // single fused convert pass (Acat, Wcat q/k/v, Wo)
    cvt_all<<<dim3(24576), 256, 0, stream>>>(hs, mu, wq, wmq, wk, wmk, wv, wmv, wo,
                                             Acat, Wcat, Wo);

    // QKV projection, split-K=2: grid 24x16x2 = 768 blocks = 3/CU
    gemm_nt_sp<<<dim3(QS / 128, SEQ / 128, 2), 256, 0, stream>>>(Acat, Wcat, qkvp, SEQ, QS, 2 * HID_DIM, HID_DIM);
    norm_rope<<<dim3(SEQ, NH + NKV), dim3(64), 0, stream>>>(qkvp, qkvp + QKVN, qw, kw);
    pack_k<<<dim3(32, NKV), 256, 0, stream>>>(qkvp, Ktl);
    pack_v<<<dim3(32, NKV), 256, 0, stream>>>(qkvp, qkvp + QKVN, Vtl);
    attn_split<<<dim3(4, 32, NH), 256, 0, stream>>>(qkvp, Ktl, Vtl, Opart, Lpart);
    combine<<<dim3(SEQ, NH), 64, 0, stream>>>(Opart, Lpart, ab);
    // output projection, split-K=4: 1024 blocks = 4/CU
    gemm_nt_sp<<<dim3(HID_DIM / 128, SEQ / 128, 4), 256, 0, stream>>>(ab, Wo, outp, SEQ, HID_DIM, NH * HD, 512);
    add4<<<dim3((1024 * 1024 + 255) / 256), 256, 0, stream>>>(outp, out, 1024 * 1024);
}